// Round 1
// baseline (213.299 us; speedup 1.0000x reference)
//
#include <hip/hip_runtime.h>

#define NB 4096
#define DK 768
#define SCALE_S 0.5295756522f

typedef float f32x4 __attribute__((ext_vector_type(4)));
typedef __bf16 bf16x8 __attribute__((ext_vector_type(8)));

// ---- ws layout (bytes) ----
#define OFF_XB      0u            // 4096*768 bf16 = 6291456
#define OFF_YB      6291456u
#define OFF_ROWPM   12582912u     // 32*4096 f32
#define OFF_ROWPS   13107200u
#define OFF_COLPM   13631488u
#define OFF_COLPS   14155776u
#define OFF_LSER    14680064u     // 4096 f32
#define OFF_LSEC    14696448u
#define OFF_BITS    14712832u     // 4096 u32
#define OFF_CSPART  14729216u     // 16*32 int
#define OFF_DOTP    14731264u     // 96 f32
#define OFF_UPART   14731648u     // 32*32*768 f32
#define OFF_VPART   17877376u     // 32*32*768 f32  (end ~21 MB)

static __device__ __forceinline__ unsigned short f2bf(float f) {
  union { float f; unsigned u; } x; x.f = f;
  unsigned r = x.u + 0x7fffu + ((x.u >> 16) & 1u);   // RNE
  return (unsigned short)(r >> 16);
}

static __device__ __forceinline__ void gload16(const void* g, void* l) {
  __builtin_amdgcn_global_load_lds(
      (const __attribute__((address_space(1))) unsigned int*)g,
      (__attribute__((address_space(3))) unsigned int*)l,
      16, 0, 0);
}

// K1: pack label-row bits + per-block column-count partials
__global__ void k_pack(const int* __restrict__ labels, unsigned* __restrict__ bits,
                       int* __restrict__ csPart) {
  __shared__ int cs[32];
  int t = threadIdx.x;
  if (t < 32) cs[t] = 0;
  __syncthreads();
  int i = blockIdx.x * 256 + t;
  const int* row = labels + (size_t)i * 32;
  unsigned b = 0;
#pragma unroll
  for (int j = 0; j < 32; ++j) if (row[j] != 0) b |= (1u << j);
  bits[i] = b;
#pragma unroll
  for (int j = 0; j < 32; ++j) if (b & (1u << j)) atomicAdd(&cs[j], 1);
  __syncthreads();
  if (t < 32) csPart[blockIdx.x * 32 + t] = cs[t];
}

// K2: fp32 -> bf16 for X and Y
__global__ void k_conv(const float* __restrict__ X, const float* __restrict__ Y,
                       unsigned short* __restrict__ Xb, unsigned short* __restrict__ Yb) {
  const int N4 = (NB * DK) / 4;  // 786432
  for (int idx = blockIdx.x * blockDim.x + threadIdx.x; idx < 2 * N4;
       idx += gridDim.x * blockDim.x) {
    float4 v; unsigned short* dst;
    if (idx < N4) { v = ((const float4*)X)[idx]; dst = Xb + (size_t)idx * 4; }
    else          { v = ((const float4*)Y)[idx - N4]; dst = Yb + (size_t)(idx - N4) * 4; }
    uint2 p;
    p.x = (unsigned)f2bf(v.x) | ((unsigned)f2bf(v.y) << 16);
    p.y = (unsigned)f2bf(v.z) | ((unsigned)f2bf(v.w) << 16);
    *(uint2*)dst = p;
  }
}

// K3: partial U = mask^T X, V = mask^T Y per 128-row chunk
__global__ void k_uv(const float* __restrict__ X, const float* __restrict__ Y,
                     const unsigned* __restrict__ bits,
                     float* __restrict__ Up, float* __restrict__ Vp) {
  int d = blockIdx.x * 256 + threadIdx.x;   // 0..767
  int chunk = blockIdx.y;                    // 0..31
  float u[32], v[32];
#pragma unroll
  for (int j = 0; j < 32; ++j) { u[j] = 0.f; v[j] = 0.f; }
  int i0 = chunk * 128;
  for (int ii = 0; ii < 128; ++ii) {
    int i = i0 + ii;
    unsigned b = bits[i];
    float x = X[(size_t)i * DK + d];
    float y = Y[(size_t)i * DK + d];
#pragma unroll
    for (int j = 0; j < 32; ++j)
      if (b & (1u << j)) { u[j] += x; v[j] += y; }
  }
  size_t base = (size_t)chunk * (32 * DK);
#pragma unroll
  for (int j = 0; j < 32; ++j) {
    Up[base + j * DK + d] = u[j];
    Vp[base + j * DK + d] = v[j];
  }
}

// K4: 128x128 bf16 MFMA GEMM tile with fused row/col (max,sumexp) epilogue
__launch_bounds__(256)
__global__ void k_gemm(const unsigned short* __restrict__ Xb,
                       const unsigned short* __restrict__ Yb,
                       float* __restrict__ rowPM, float* __restrict__ rowPS,
                       float* __restrict__ colPM, float* __restrict__ colPS) {
  __shared__ unsigned short As[128][32];
  __shared__ unsigned short Bs[128][32];
  __shared__ float redM[128][2], redS[128][2], redM2[128][2], redS2[128][2];

  const int t = threadIdx.x;
  const int wave = t >> 6, lane = t & 63;
  const int cb = blockIdx.x, rb = blockIdx.y;

  // staging: each thread 16B; row = t/4, col8 = (t%4)*8; issue1 = rows 64..127
  const int srow = t >> 2;
  const int scol = (t & 3) * 8;
  const unsigned short* ga = Xb + (size_t)(rb * 128 + srow) * DK + scol;
  const unsigned short* gb = Yb + (size_t)(cb * 128 + srow) * DK + scol;
  unsigned short* la = &As[0][0] + wave * 512;   // wave-uniform LDS base
  unsigned short* lb = &Bs[0][0] + wave * 512;

  f32x4 acc[4][4];
#pragma unroll
  for (int m = 0; m < 4; ++m)
#pragma unroll
    for (int n = 0; n < 4; ++n) acc[m][n] = (f32x4){0.f, 0.f, 0.f, 0.f};

  const int wr = wave >> 1, wc = wave & 1;
  const int lrow = lane & 15;
  const int kch = (lane >> 4) * 8;

  for (int kt = 0; kt < DK / 32; ++kt) {
    __syncthreads();
    gload16(ga + kt * 32, la);
    gload16(ga + kt * 32 + (size_t)64 * DK, la + 2048);
    gload16(gb + kt * 32, lb);
    gload16(gb + kt * 32 + (size_t)64 * DK, lb + 2048);
    __syncthreads();
    bf16x8 af[4], bf[4];
#pragma unroll
    for (int m = 0; m < 4; ++m) af[m] = *(const bf16x8*)&As[wr * 64 + m * 16 + lrow][kch];
#pragma unroll
    for (int n = 0; n < 4; ++n) bf[n] = *(const bf16x8*)&Bs[wc * 64 + n * 16 + lrow][kch];
#pragma unroll
    for (int m = 0; m < 4; ++m)
#pragma unroll
      for (int n = 0; n < 4; ++n)
        acc[m][n] = __builtin_amdgcn_mfma_f32_16x16x32_bf16(af[m], bf[n], acc[m][n], 0, 0, 0);
  }

  // ---- epilogue: per-row and per-col (max, sumexp) over this 128x128 tile ----
  // C/D layout: col = lane&15, row = (lane>>4)*4 + reg  [learn_hip m89/m91]
#pragma unroll
  for (int m = 0; m < 4; ++m) {
#pragma unroll
    for (int r = 0; r < 4; ++r) {
      float v0 = SCALE_S * acc[m][0][r];
      float v1 = SCALE_S * acc[m][1][r];
      float v2 = SCALE_S * acc[m][2][r];
      float v3 = SCALE_S * acc[m][3][r];
      float mx = fmaxf(fmaxf(v0, v1), fmaxf(v2, v3));
#pragma unroll
      for (int off = 1; off < 16; off <<= 1) mx = fmaxf(mx, __shfl_xor(mx, off));
      float sm = __expf(v0 - mx) + __expf(v1 - mx) + __expf(v2 - mx) + __expf(v3 - mx);
#pragma unroll
      for (int off = 1; off < 16; off <<= 1) sm += __shfl_xor(sm, off);
      if ((lane & 15) == 0) {
        int row = wr * 64 + m * 16 + (lane >> 4) * 4 + r;
        redM[row][wc] = mx; redS[row][wc] = sm;
      }
    }
  }
#pragma unroll
  for (int n = 0; n < 4; ++n) {
    float mx = -3.0e38f;
#pragma unroll
    for (int m = 0; m < 4; ++m)
#pragma unroll
      for (int r = 0; r < 4; ++r) mx = fmaxf(mx, SCALE_S * acc[m][n][r]);
    mx = fmaxf(mx, __shfl_xor(mx, 16));
    mx = fmaxf(mx, __shfl_xor(mx, 32));
    float sm = 0.f;
#pragma unroll
    for (int m = 0; m < 4; ++m)
#pragma unroll
      for (int r = 0; r < 4; ++r) sm += __expf(SCALE_S * acc[m][n][r] - mx);
    sm += __shfl_xor(sm, 16);
    sm += __shfl_xor(sm, 32);
    if (lane < 16) {
      int col = wc * 64 + n * 16 + lane;
      redM2[col][wr] = mx; redS2[col][wr] = sm;
    }
  }
  __syncthreads();
  if (t < 128) {
    float m0 = redM[t][0], m1 = redM[t][1];
    float M = fmaxf(m0, m1);
    float S = redS[t][0] * __expf(m0 - M) + redS[t][1] * __expf(m1 - M);
    rowPM[(size_t)cb * NB + rb * 128 + t] = M;
    rowPS[(size_t)cb * NB + rb * 128 + t] = S;
  } else {
    int c = t - 128;
    float m0 = redM2[c][0], m1 = redM2[c][1];
    float M = fmaxf(m0, m1);
    float S = redS2[c][0] * __expf(m0 - M) + redS2[c][1] * __expf(m1 - M);
    colPM[(size_t)rb * NB + cb * 128 + c] = M;
    colPS[(size_t)rb * NB + cb * 128 + c] = S;
  }
}

// K5: combine 32 (max,sumexp) partials per row/col -> lse
__global__ void k_comb(const float* __restrict__ rowPM, const float* __restrict__ rowPS,
                       const float* __restrict__ colPM, const float* __restrict__ colPS,
                       float* __restrict__ lse_r, float* __restrict__ lse_c) {
  int g = blockIdx.x * 256 + threadIdx.x;  // 0..8191
  const float* pM; const float* pS; float* out; int i;
  if (g < NB) { pM = rowPM; pS = rowPS; out = lse_r; i = g; }
  else        { pM = colPM; pS = colPS; out = lse_c; i = g - NB; }
  float M = -3.0e38f;
#pragma unroll
  for (int c = 0; c < 32; ++c) M = fmaxf(M, pM[(size_t)c * NB + i]);
  float S = 0.f;
#pragma unroll
  for (int c = 0; c < 32; ++c) S += pS[(size_t)c * NB + i] * __expf(pM[(size_t)c * NB + i] - M);
  out[i] = M + __logf(S);
}

// K6: reduce U,V chunks and form per-block dot partials
__global__ void k_uvred(const float* __restrict__ Up, const float* __restrict__ Vp,
                        float* __restrict__ dotPart) {
  int e = blockIdx.x * 256 + threadIdx.x;  // 0..24575
  float U = 0.f, V = 0.f;
#pragma unroll 8
  for (int c = 0; c < 32; ++c) { U += Up[(size_t)c * 24576 + e]; V += Vp[(size_t)c * 24576 + e]; }
  float p = U * V;
#pragma unroll
  for (int off = 32; off; off >>= 1) p += __shfl_down(p, off);
  __shared__ float red[4];
  if ((threadIdx.x & 63) == 0) red[threadIdx.x >> 6] = p;
  __syncthreads();
  if (threadIdx.x == 0) dotPart[blockIdx.x] = red[0] + red[1] + red[2] + red[3];
}

// K7: finalize scalar loss
__global__ void k_final(const unsigned* __restrict__ bits, const int* __restrict__ csPart,
                        const float* __restrict__ lse_r, const float* __restrict__ lse_c,
                        const float* __restrict__ dotPart, float* __restrict__ out) {
  __shared__ int cs[32];
  __shared__ double red[256];
  int t = threadIdx.x;
  if (t < 32) {
    int s = 0;
    for (int b = 0; b < 16; ++b) s += csPart[b * 32 + t];
    cs[t] = s;
  }
  __syncthreads();
  double acc = 0.0;
  for (int i = t; i < NB; i += 256) {
    unsigned b = bits[i];
    int rw = 0;
#pragma unroll
    for (int j = 0; j < 32; ++j) if (b & (1u << j)) rw += cs[j];
    acc += (double)rw * ((double)lse_r[i] + (double)lse_c[i]);
  }
  if (t < 96) acc -= 2.0 * (double)SCALE_S * (double)dotPart[t];
  red[t] = acc;
  __syncthreads();
  for (int s = 128; s; s >>= 1) {
    if (t < s) red[t] += red[t + s];
    __syncthreads();
  }
  if (t == 0) out[0] = (float)(red[0] / (2.0 * (double)NB * 32.0));
}

extern "C" void kernel_launch(void* const* d_in, const int* in_sizes, int n_in,
                              void* d_out, int out_size, void* d_ws, size_t ws_size,
                              hipStream_t stream) {
  const float* X = (const float*)d_in[0];
  const float* Y = (const float*)d_in[1];
  const int* labels = (const int*)d_in[2];
  char* ws = (char*)d_ws;

  unsigned short* Xb = (unsigned short*)(ws + OFF_XB);
  unsigned short* Yb = (unsigned short*)(ws + OFF_YB);
  float* rowPM = (float*)(ws + OFF_ROWPM);
  float* rowPS = (float*)(ws + OFF_ROWPS);
  float* colPM = (float*)(ws + OFF_COLPM);
  float* colPS = (float*)(ws + OFF_COLPS);
  float* lse_r = (float*)(ws + OFF_LSER);
  float* lse_c = (float*)(ws + OFF_LSEC);
  unsigned* bits = (unsigned*)(ws + OFF_BITS);
  int* csPart = (int*)(ws + OFF_CSPART);
  float* dotPart = (float*)(ws + OFF_DOTP);
  float* Up = (float*)(ws + OFF_UPART);
  float* Vp = (float*)(ws + OFF_VPART);

  k_pack<<<16, 256, 0, stream>>>(labels, bits, csPart);
  k_conv<<<1024, 256, 0, stream>>>(X, Y, Xb, Yb);
  k_uv<<<dim3(3, 32), 256, 0, stream>>>(X, Y, bits, Up, Vp);
  k_gemm<<<dim3(32, 32), 256, 0, stream>>>(Xb, Yb, rowPM, rowPS, colPM, colPS);
  k_comb<<<32, 256, 0, stream>>>(rowPM, rowPS, colPM, colPS, lse_r, lse_c);
  k_uvred<<<96, 256, 0, stream>>>(Up, Vp, dotPart);
  k_final<<<1, 256, 0, stream>>>(bits, csPart, lse_r, lse_c, dotPart, (float*)d_out);
}

// Round 2
// 113.921 us; speedup vs baseline: 1.8723x; 1.8723x over previous
//
#include <hip/hip_runtime.h>

#define NB 4096
#define DK 768
#define SCALE_S 0.5295756522f

typedef float f32x4 __attribute__((ext_vector_type(4)));
typedef __bf16 bf16x8 __attribute__((ext_vector_type(8)));

// ---- ws layout (bytes) ----
#define OFF_XB      0u            // 4096*768 bf16 = 6291456
#define OFF_YB      6291456u
#define OFF_ROWPM   12582912u     // 32*4096 f32
#define OFF_ROWPS   13107200u
#define OFF_COLPM   13631488u
#define OFF_COLPS   14155776u
#define OFF_LSER    14680064u     // 4096 f32
#define OFF_LSEC    14696448u
#define OFF_BITS    14712832u     // 4096 u32
#define OFF_CSPART  14729216u     // 16*32 int
#define OFF_DOTP    14731264u     // 96 f32
#define OFF_UPART   14731648u     // 32*32*768 f32
#define OFF_VPART   17877376u     // 32*32*768 f32  (end ~21 MB)

static __device__ __forceinline__ unsigned short f2bf(float f) {
  union { float f; unsigned u; } x; x.f = f;
  unsigned r = x.u + 0x7fffu + ((x.u >> 16) & 1u);   // RNE
  return (unsigned short)(r >> 16);
}

static __device__ __forceinline__ void gload16(const void* g, void* l) {
  __builtin_amdgcn_global_load_lds(
      (const __attribute__((address_space(1))) unsigned int*)g,
      (__attribute__((address_space(3))) unsigned int*)l,
      16, 0, 0);
}

// K1: pack label-row bits + per-block column-count partials
__global__ void k_pack(const int* __restrict__ labels, unsigned* __restrict__ bits,
                       int* __restrict__ csPart) {
  __shared__ int cs[32];
  int t = threadIdx.x;
  if (t < 32) cs[t] = 0;
  __syncthreads();
  int i = blockIdx.x * 256 + t;
  const int* row = labels + (size_t)i * 32;
  unsigned b = 0;
#pragma unroll
  for (int j = 0; j < 32; ++j) if (row[j] != 0) b |= (1u << j);
  bits[i] = b;
#pragma unroll
  for (int j = 0; j < 32; ++j) if (b & (1u << j)) atomicAdd(&cs[j], 1);
  __syncthreads();
  if (t < 32) csPart[blockIdx.x * 32 + t] = cs[t];
}

// K2: fp32 -> bf16 for X and Y
__global__ void k_conv(const float* __restrict__ X, const float* __restrict__ Y,
                       unsigned short* __restrict__ Xb, unsigned short* __restrict__ Yb) {
  const int N4 = (NB * DK) / 4;  // 786432
  for (int idx = blockIdx.x * blockDim.x + threadIdx.x; idx < 2 * N4;
       idx += gridDim.x * blockDim.x) {
    float4 v; unsigned short* dst;
    if (idx < N4) { v = ((const float4*)X)[idx]; dst = Xb + (size_t)idx * 4; }
    else          { v = ((const float4*)Y)[idx - N4]; dst = Yb + (size_t)(idx - N4) * 4; }
    uint2 p;
    p.x = (unsigned)f2bf(v.x) | ((unsigned)f2bf(v.y) << 16);
    p.y = (unsigned)f2bf(v.z) | ((unsigned)f2bf(v.w) << 16);
    *(uint2*)dst = p;
  }
}

// K3: partial U = mask^T X, V = mask^T Y per 128-row chunk, 8 j's per block
// (j split across blockIdx.z so accumulators fit in VGPRs — no scratch)
__global__ void k_uv(const float* __restrict__ X, const float* __restrict__ Y,
                     const unsigned* __restrict__ bits,
                     float* __restrict__ Up, float* __restrict__ Vp) {
  int d = blockIdx.x * 256 + threadIdx.x;   // 0..767
  int chunk = blockIdx.y;                    // 0..31
  int jg = blockIdx.z;                       // 0..3
  float u[8], v[8];
#pragma unroll
  for (int j = 0; j < 8; ++j) { u[j] = 0.f; v[j] = 0.f; }
  int i0 = chunk * 128;
#pragma unroll 2
  for (int ii = 0; ii < 128; ++ii) {
    int i = i0 + ii;
    unsigned b = bits[i] >> (jg * 8);
    float x = X[(size_t)i * DK + d];
    float y = Y[(size_t)i * DK + d];
#pragma unroll
    for (int j = 0; j < 8; ++j) {
      bool m = (b >> j) & 1u;
      u[j] += m ? x : 0.f;
      v[j] += m ? y : 0.f;
    }
  }
  size_t base = (size_t)chunk * (32 * DK) + (size_t)jg * (8 * DK);
#pragma unroll
  for (int j = 0; j < 8; ++j) {
    Up[base + j * DK + d] = u[j];
    Vp[base + j * DK + d] = v[j];
  }
}

// K4: 128x128 bf16 MFMA GEMM tile with fused row/col (max,sumexp) epilogue
__launch_bounds__(256)
__global__ void k_gemm(const unsigned short* __restrict__ Xb,
                       const unsigned short* __restrict__ Yb,
                       float* __restrict__ rowPM, float* __restrict__ rowPS,
                       float* __restrict__ colPM, float* __restrict__ colPS) {
  __shared__ unsigned short As[128][32];
  __shared__ unsigned short Bs[128][32];
  __shared__ float redM[128][2], redS[128][2], redM2[128][2], redS2[128][2];

  const int t = threadIdx.x;
  const int wave = t >> 6, lane = t & 63;
  const int cb = blockIdx.x, rb = blockIdx.y;

  // staging: each thread 16B; row = t/4, col8 = (t%4)*8; issue1 = rows 64..127
  const int srow = t >> 2;
  const int scol = (t & 3) * 8;
  const unsigned short* ga = Xb + (size_t)(rb * 128 + srow) * DK + scol;
  const unsigned short* gb = Yb + (size_t)(cb * 128 + srow) * DK + scol;
  unsigned short* la = &As[0][0] + wave * 512;   // wave-uniform LDS base
  unsigned short* lb = &Bs[0][0] + wave * 512;

  f32x4 acc[4][4];
#pragma unroll
  for (int m = 0; m < 4; ++m)
#pragma unroll
    for (int n = 0; n < 4; ++n) acc[m][n] = (f32x4){0.f, 0.f, 0.f, 0.f};

  const int wr = wave >> 1, wc = wave & 1;
  const int lrow = lane & 15;
  const int kch = (lane >> 4) * 8;

  for (int kt = 0; kt < DK / 32; ++kt) {
    __syncthreads();
    gload16(ga + kt * 32, la);
    gload16(ga + kt * 32 + (size_t)64 * DK, la + 2048);
    gload16(gb + kt * 32, lb);
    gload16(gb + kt * 32 + (size_t)64 * DK, lb + 2048);
    __syncthreads();
    bf16x8 af[4], bf[4];
#pragma unroll
    for (int m = 0; m < 4; ++m) af[m] = *(const bf16x8*)&As[wr * 64 + m * 16 + lrow][kch];
#pragma unroll
    for (int n = 0; n < 4; ++n) bf[n] = *(const bf16x8*)&Bs[wc * 64 + n * 16 + lrow][kch];
#pragma unroll
    for (int m = 0; m < 4; ++m)
#pragma unroll
      for (int n = 0; n < 4; ++n)
        acc[m][n] = __builtin_amdgcn_mfma_f32_16x16x32_bf16(af[m], bf[n], acc[m][n], 0, 0, 0);
  }

  // ---- epilogue: per-row and per-col (max, sumexp) over this 128x128 tile ----
  // C/D layout: col = lane&15, row = (lane>>4)*4 + reg  [learn_hip m89/m91]
#pragma unroll
  for (int m = 0; m < 4; ++m) {
#pragma unroll
    for (int r = 0; r < 4; ++r) {
      float v0 = SCALE_S * acc[m][0][r];
      float v1 = SCALE_S * acc[m][1][r];
      float v2 = SCALE_S * acc[m][2][r];
      float v3 = SCALE_S * acc[m][3][r];
      float mx = fmaxf(fmaxf(v0, v1), fmaxf(v2, v3));
#pragma unroll
      for (int off = 1; off < 16; off <<= 1) mx = fmaxf(mx, __shfl_xor(mx, off));
      float sm = __expf(v0 - mx) + __expf(v1 - mx) + __expf(v2 - mx) + __expf(v3 - mx);
#pragma unroll
      for (int off = 1; off < 16; off <<= 1) sm += __shfl_xor(sm, off);
      if ((lane & 15) == 0) {
        int row = wr * 64 + m * 16 + (lane >> 4) * 4 + r;
        redM[row][wc] = mx; redS[row][wc] = sm;
      }
    }
  }
#pragma unroll
  for (int n = 0; n < 4; ++n) {
    float mx = -3.0e38f;
#pragma unroll
    for (int m = 0; m < 4; ++m)
#pragma unroll
      for (int r = 0; r < 4; ++r) mx = fmaxf(mx, SCALE_S * acc[m][n][r]);
    mx = fmaxf(mx, __shfl_xor(mx, 16));
    mx = fmaxf(mx, __shfl_xor(mx, 32));
    float sm = 0.f;
#pragma unroll
    for (int m = 0; m < 4; ++m)
#pragma unroll
      for (int r = 0; r < 4; ++r) sm += __expf(SCALE_S * acc[m][n][r] - mx);
    sm += __shfl_xor(sm, 16);
    sm += __shfl_xor(sm, 32);
    if (lane < 16) {
      int col = wc * 64 + n * 16 + lane;
      redM2[col][wr] = mx; redS2[col][wr] = sm;
    }
  }
  __syncthreads();
  if (t < 128) {
    float m0 = redM[t][0], m1 = redM[t][1];
    float M = fmaxf(m0, m1);
    float S = redS[t][0] * __expf(m0 - M) + redS[t][1] * __expf(m1 - M);
    rowPM[(size_t)cb * NB + rb * 128 + t] = M;
    rowPS[(size_t)cb * NB + rb * 128 + t] = S;
  } else {
    int c = t - 128;
    float m0 = redM2[c][0], m1 = redM2[c][1];
    float M = fmaxf(m0, m1);
    float S = redS2[c][0] * __expf(m0 - M) + redS2[c][1] * __expf(m1 - M);
    colPM[(size_t)rb * NB + cb * 128 + c] = M;
    colPS[(size_t)rb * NB + cb * 128 + c] = S;
  }
}

// K5: combine 32 (max,sumexp) partials per row/col -> lse
__global__ void k_comb(const float* __restrict__ rowPM, const float* __restrict__ rowPS,
                       const float* __restrict__ colPM, const float* __restrict__ colPS,
                       float* __restrict__ lse_r, float* __restrict__ lse_c) {
  int g = blockIdx.x * 256 + threadIdx.x;  // 0..8191
  const float* pM; const float* pS; float* out; int i;
  if (g < NB) { pM = rowPM; pS = rowPS; out = lse_r; i = g; }
  else        { pM = colPM; pS = colPS; out = lse_c; i = g - NB; }
  float M = -3.0e38f;
#pragma unroll
  for (int c = 0; c < 32; ++c) M = fmaxf(M, pM[(size_t)c * NB + i]);
  float S = 0.f;
#pragma unroll
  for (int c = 0; c < 32; ++c) S += pS[(size_t)c * NB + i] * __expf(pM[(size_t)c * NB + i] - M);
  out[i] = M + __logf(S);
}

// K6: reduce U,V chunks and form per-block dot partials
__global__ void k_uvred(const float* __restrict__ Up, const float* __restrict__ Vp,
                        float* __restrict__ dotPart) {
  int e = blockIdx.x * 256 + threadIdx.x;  // 0..24575
  float U = 0.f, V = 0.f;
#pragma unroll 8
  for (int c = 0; c < 32; ++c) { U += Up[(size_t)c * 24576 + e]; V += Vp[(size_t)c * 24576 + e]; }
  float p = U * V;
#pragma unroll
  for (int off = 32; off; off >>= 1) p += __shfl_down(p, off);
  __shared__ float red[4];
  if ((threadIdx.x & 63) == 0) red[threadIdx.x >> 6] = p;
  __syncthreads();
  if (threadIdx.x == 0) dotPart[blockIdx.x] = red[0] + red[1] + red[2] + red[3];
}

// K7: finalize scalar loss
__global__ void k_final(const unsigned* __restrict__ bits, const int* __restrict__ csPart,
                        const float* __restrict__ lse_r, const float* __restrict__ lse_c,
                        const float* __restrict__ dotPart, float* __restrict__ out) {
  __shared__ int cs[32];
  __shared__ double red[256];
  int t = threadIdx.x;
  if (t < 32) {
    int s = 0;
    for (int b = 0; b < 16; ++b) s += csPart[b * 32 + t];
    cs[t] = s;
  }
  __syncthreads();
  double acc = 0.0;
  for (int i = t; i < NB; i += 256) {
    unsigned b = bits[i];
    int rw = 0;
#pragma unroll
    for (int j = 0; j < 32; ++j) if (b & (1u << j)) rw += cs[j];
    acc += (double)rw * ((double)lse_r[i] + (double)lse_c[i]);
  }
  if (t < 96) acc -= 2.0 * (double)SCALE_S * (double)dotPart[t];
  red[t] = acc;
  __syncthreads();
  for (int s = 128; s; s >>= 1) {
    if (t < s) red[t] += red[t + s];
    __syncthreads();
  }
  if (t == 0) out[0] = (float)(red[0] / (2.0 * (double)NB * 32.0));
}

extern "C" void kernel_launch(void* const* d_in, const int* in_sizes, int n_in,
                              void* d_out, int out_size, void* d_ws, size_t ws_size,
                              hipStream_t stream) {
  const float* X = (const float*)d_in[0];
  const float* Y = (const float*)d_in[1];
  const int* labels = (const int*)d_in[2];
  char* ws = (char*)d_ws;

  unsigned short* Xb = (unsigned short*)(ws + OFF_XB);
  unsigned short* Yb = (unsigned short*)(ws + OFF_YB);
  float* rowPM = (float*)(ws + OFF_ROWPM);
  float* rowPS = (float*)(ws + OFF_ROWPS);
  float* colPM = (float*)(ws + OFF_COLPM);
  float* colPS = (float*)(ws + OFF_COLPS);
  float* lse_r = (float*)(ws + OFF_LSER);
  float* lse_c = (float*)(ws + OFF_LSEC);
  unsigned* bits = (unsigned*)(ws + OFF_BITS);
  int* csPart = (int*)(ws + OFF_CSPART);
  float* dotPart = (float*)(ws + OFF_DOTP);
  float* Up = (float*)(ws + OFF_UPART);
  float* Vp = (float*)(ws + OFF_VPART);

  k_pack<<<16, 256, 0, stream>>>(labels, bits, csPart);
  k_conv<<<1024, 256, 0, stream>>>(X, Y, Xb, Yb);
  k_uv<<<dim3(3, 32, 4), 256, 0, stream>>>(X, Y, bits, Up, Vp);
  k_gemm<<<dim3(32, 32), 256, 0, stream>>>(Xb, Yb, rowPM, rowPS, colPM, colPS);
  k_comb<<<32, 256, 0, stream>>>(rowPM, rowPS, colPM, colPS, lse_r, lse_c);
  k_uvred<<<96, 256, 0, stream>>>(Up, Vp, dotPart);
  k_final<<<1, 256, 0, stream>>>(bits, csPart, lse_r, lse_c, dotPart, (float*)d_out);
}